// Round 1
// baseline (354.880 us; speedup 1.0000x reference)
//
#include <hip/hip_runtime.h>
#include <math.h>

#define NTOK (16 * 8192)   // 131072 tokens
#define H    256
#define E    32
#define SEQ  8192
#define BSZ  16

// ---------------- zero the workspace accumulators ----------------
__global__ __launch_bounds__(256) void zero_ws_kernel(float* ws) {
    int i = blockIdx.x * 256 + threadIdx.x;
    if (i < BSZ * E * 2) ws[i] = 0.0f;
}

// ---------------- main gate kernel: logits -> softmax -> top1 + bin accum ----
__global__ __launch_bounds__(256, 2) void gate_kernel(
    const float* __restrict__ x, const float* __restrict__ w,
    float* __restrict__ out, float* __restrict__ ws_cnt, float* __restrict__ ws_sum)
{
    const int tid   = threadIdx.x;
    const int token = blockIdx.x * 256 + tid;
    const int lane  = tid & 63;

    float acc[E];
#pragma unroll
    for (int e = 0; e < E; ++e) acc[e] = 0.0f;

    const float* xrow = x + (size_t)token * H;

    // h loop: 64B of x per lane per step (consume full cache lines),
    // w indices are wave-uniform -> scalar loads expected.
#pragma unroll 1
    for (int h = 0; h < H; h += 16) {
        float4 xv[4];
#pragma unroll
        for (int j = 0; j < 4; ++j)
            xv[j] = *(const float4*)(xrow + h + 4 * j);
#pragma unroll
        for (int e = 0; e < E; ++e) {
            const float* wrow = w + e * H + h;
            float s = 0.0f;
#pragma unroll
            for (int j = 0; j < 4; ++j) {
                float4 wv = *(const float4*)(wrow + 4 * j);
                s += xv[j].x * wv.x + xv[j].y * wv.y + xv[j].z * wv.z + xv[j].w * wv.w;
            }
            acc[e] += s;
        }
    }

    // argmax (first occurrence wins, matches jax top_k tie-break) + softmax denom
    float m = acc[0];
    int   idx = 0;
#pragma unroll
    for (int e = 1; e < E; ++e) {
        if (acc[e] > m) { m = acc[e]; idx = e; }
    }
    float sc[E];
    float ssum = 0.0f;
#pragma unroll
    for (int e = 0; e < E; ++e) {
        sc[e] = expf(acc[e] - m);
        ssum += sc[e];
    }
    const float inv = 1.0f / ssum;   // == softmax score at argmax; SCALING = 1.0

    out[token]        = (float)idx;
    out[NTOK + token] = inv;

    // ---- per-(batch, expert) accumulation for aux loss ----
    const int b = token / SEQ;  // wave-uniform (SEQ % 64 == 0)

#pragma unroll 1
    for (int e = 0; e < E; ++e) {
        // expert-selection count via ballot
        unsigned long long ball = __ballot(idx == e);
        if (lane == 0 && ball)
            atomicAdd(&ws_cnt[b * E + e], (float)__popcll(ball));
        // score sum via 64-lane butterfly
        float v = sc[e] * inv;
#pragma unroll
        for (int off = 32; off > 0; off >>= 1)
            v += __shfl_xor(v, off, 64);
        if (lane == 0)
            atomicAdd(&ws_sum[b * E + e], v);
    }
}

// ---------------- aux loss reduction ----------------
__global__ __launch_bounds__(256) void aux_kernel(
    const float* __restrict__ ws_cnt, const float* __restrict__ ws_sum,
    float* __restrict__ out)
{
    const int tid = threadIdx.x;
    float p = 0.0f;
    for (int i = tid; i < BSZ * E; i += 256)
        p += ws_cnt[i] * ws_sum[i];

    __shared__ float red[4];
#pragma unroll
    for (int off = 32; off > 0; off >>= 1)
        p += __shfl_xor(p, off, 64);
    if ((tid & 63) == 0) red[tid >> 6] = p;
    __syncthreads();
    if (tid == 0) {
        float t = red[0] + red[1] + red[2] + red[3];
        // aux = alpha/B * sum_be (cnt/ (SEQ/E)) * (ssum/SEQ)
        //     = sum_be cnt*ssum * alpha / (B * (SEQ/E) * SEQ)
        out[2 * NTOK] = t * (0.001f / (16.0f * 256.0f * 8192.0f));
    }
}

extern "C" void kernel_launch(void* const* d_in, const int* in_sizes, int n_in,
                              void* d_out, int out_size, void* d_ws, size_t ws_size,
                              hipStream_t stream) {
    const float* x = (const float*)d_in[0];
    const float* w = (const float*)d_in[1];
    float* out    = (float*)d_out;
    float* ws     = (float*)d_ws;
    float* ws_cnt = ws;
    float* ws_sum = ws + BSZ * E;

    zero_ws_kernel<<<4, 256, 0, stream>>>(ws);
    gate_kernel<<<NTOK / 256, 256, 0, stream>>>(x, w, out, ws_cnt, ws_sum);
    aux_kernel<<<1, 256, 0, stream>>>(ws_cnt, ws_sum, out);
}

// Round 2
// 284.931 us; speedup vs baseline: 1.2455x; 1.2455x over previous
//
#include <hip/hip_runtime.h>
#include <math.h>

#define NTOK (16 * 8192)   // 131072 tokens
#define H    256
#define E    32
#define SEQ  8192
#define BSZ  16

// ---------------- zero the workspace accumulators ----------------
__global__ __launch_bounds__(256) void zero_ws_kernel(float* ws) {
    int i = blockIdx.x * 256 + threadIdx.x;
    if (i < BSZ * E * 2) ws[i] = 0.0f;
}

// ---------------- main gate kernel: logits -> softmax -> top1 + bin accum ----
// w staged in LDS (32 KB), read wave-uniform => HW broadcast, no bank conflicts,
// no VMEM traffic for w. x streamed from global with 2-stage prefetch pipeline.
__global__ __launch_bounds__(256, 2) void gate_kernel(
    const float* __restrict__ x, const float* __restrict__ w,
    float* __restrict__ out, float* __restrict__ ws_cnt, float* __restrict__ ws_sum)
{
    __shared__ float w_lds[E * H];   // [e][h] row-major, 32 KB

    const int tid   = threadIdx.x;
    const int token = blockIdx.x * 256 + tid;
    const int lane  = tid & 63;

    // ---- stage w into LDS (coalesced float4) ----
    {
        float4*       wl = (float4*)w_lds;
        const float4* wg = (const float4*)w;
#pragma unroll
        for (int i = 0; i < (E * H / 4) / 256; ++i)
            wl[tid + 256 * i] = wg[tid + 256 * i];
    }
    __syncthreads();

    float acc[E];
#pragma unroll
    for (int e = 0; e < E; ++e) acc[e] = 0.0f;

    const float* xrow = x + (size_t)token * H;

    // ---- main loop: 16 h per step, prefetch next step's x chunk ----
    float4 cur[4], nxt[4];
#pragma unroll
    for (int j = 0; j < 4; ++j)
        cur[j] = *(const float4*)(xrow + 4 * j);

#pragma unroll 1
    for (int h = 0; h < H; h += 16) {
        const int hn = (h + 16) & (H - 1);   // wraps to 0 on last iter (stays in-bounds, L1-hot)
#pragma unroll
        for (int j = 0; j < 4; ++j)
            nxt[j] = *(const float4*)(xrow + hn + 4 * j);

#pragma unroll
        for (int e = 0; e < E; ++e) {
            const float4* wp = (const float4*)(w_lds + e * H + h);  // wave-uniform -> broadcast
            float s = 0.0f;
#pragma unroll
            for (int j = 0; j < 4; ++j) {
                float4 wv = wp[j];
                s += cur[j].x * wv.x + cur[j].y * wv.y + cur[j].z * wv.z + cur[j].w * wv.w;
            }
            acc[e] += s;
        }
#pragma unroll
        for (int j = 0; j < 4; ++j) cur[j] = nxt[j];
    }

    // ---- argmax (first occurrence wins) + softmax denom ----
    float m = acc[0];
    int   idx = 0;
#pragma unroll
    for (int e = 1; e < E; ++e) {
        if (acc[e] > m) { m = acc[e]; idx = e; }
    }
    float sc[E];
    float ssum = 0.0f;
#pragma unroll
    for (int e = 0; e < E; ++e) {
        sc[e] = expf(acc[e] - m);
        ssum += sc[e];
    }
    const float inv = 1.0f / ssum;   // softmax score at argmax; SCALING = 1.0

    out[token]        = (float)idx;
    out[NTOK + token] = inv;

    // ---- per-(batch, expert) accumulation for aux loss ----
    const int b = token / SEQ;  // wave-uniform (SEQ % 64 == 0)

#pragma unroll 1
    for (int e = 0; e < E; ++e) {
        unsigned long long ball = __ballot(idx == e);
        if (lane == 0 && ball)
            atomicAdd(&ws_cnt[b * E + e], (float)__popcll(ball));
        float v = sc[e] * inv;
#pragma unroll
        for (int off = 32; off > 0; off >>= 1)
            v += __shfl_xor(v, off, 64);
        if (lane == 0)
            atomicAdd(&ws_sum[b * E + e], v);
    }
}

// ---------------- aux loss reduction ----------------
__global__ __launch_bounds__(256) void aux_kernel(
    const float* __restrict__ ws_cnt, const float* __restrict__ ws_sum,
    float* __restrict__ out)
{
    const int tid = threadIdx.x;
    float p = 0.0f;
    for (int i = tid; i < BSZ * E; i += 256)
        p += ws_cnt[i] * ws_sum[i];

    __shared__ float red[4];
#pragma unroll
    for (int off = 32; off > 0; off >>= 1)
        p += __shfl_xor(p, off, 64);
    if ((tid & 63) == 0) red[tid >> 6] = p;
    __syncthreads();
    if (tid == 0) {
        float t = red[0] + red[1] + red[2] + red[3];
        // aux = sum_be cnt*ssum * alpha / (B * (SEQ/E) * SEQ)
        out[2 * NTOK] = t * (0.001f / (16.0f * 256.0f * 8192.0f));
    }
}

extern "C" void kernel_launch(void* const* d_in, const int* in_sizes, int n_in,
                              void* d_out, int out_size, void* d_ws, size_t ws_size,
                              hipStream_t stream) {
    const float* x = (const float*)d_in[0];
    const float* w = (const float*)d_in[1];
    float* out    = (float*)d_out;
    float* ws     = (float*)d_ws;
    float* ws_cnt = ws;
    float* ws_sum = ws + BSZ * E;

    zero_ws_kernel<<<4, 256, 0, stream>>>(ws);
    gate_kernel<<<NTOK / 256, 256, 0, stream>>>(x, w, out, ws_cnt, ws_sum);
    aux_kernel<<<1, 256, 0, stream>>>(ws_cnt, ws_sum, out);
}

// Round 3
// 272.742 us; speedup vs baseline: 1.3012x; 1.0447x over previous
//
#include <hip/hip_runtime.h>
#include <math.h>

#define NTOK (16 * 8192)   // 131072 tokens
#define H    256
#define E    32
#define SEQ  8192
#define BSZ  16
#define T    4             // tokens per thread (w-read amortization)

// ---------------- zero the workspace accumulators ----------------
__global__ __launch_bounds__(256) void zero_ws_kernel(float* ws) {
    int i = blockIdx.x * 256 + threadIdx.x;
    if (i < BSZ * E * 2) ws[i] = 0.0f;
}

// ---------------- main gate kernel ----------------
// Layout: 128 threads = 2 waves. Wave = 32 token-columns x 2 h-halves.
// Each thread: T=4 tokens, h-half (128 of 256). acc[32][4] partials,
// combined across halves via shfl_xor(32). Each lane finishes 2 tokens.
// w in LDS; one ds_read_b128 feeds 16 FMAs (4 tokens x 4 h).
__global__ __launch_bounds__(128, 2) void gate_kernel(
    const float* __restrict__ x, const float* __restrict__ w,
    float* __restrict__ out, float* __restrict__ ws_cnt, float* __restrict__ ws_sum)
{
    __shared__ float w_lds[E * H];   // 32 KB, [e][h]

    const int tid = threadIdx.x;

    // ---- stage w into LDS (coalesced float4: 16 per thread) ----
    {
        float4*       wl = (float4*)w_lds;
        const float4* wg = (const float4*)w;
#pragma unroll
        for (int i = 0; i < (E * H / 4) / 128; ++i)
            wl[tid + 128 * i] = wg[tid + 128 * i];
    }
    __syncthreads();

    const int lane = tid & 63;
    const int col  = lane & 31;       // token column
    const int half = lane >> 5;       // h-half: 0 -> h[0:128), 1 -> h[128:256)
    const int wavebase = blockIdx.x * 256 + (tid >> 6) * 128;
    const int tok0 = wavebase + col * T;

    const float* xbase = x + (size_t)tok0 * H + half * 128;

    float acc[E][T];
#pragma unroll
    for (int e = 0; e < E; ++e)
#pragma unroll
        for (int t = 0; t < T; ++t) acc[e][t] = 0.0f;

    // ---- main loop over my 128-h half, 4 h per step ----
    float4 cur[T], nxt[T];
#pragma unroll
    for (int t = 0; t < T; ++t)
        cur[t] = *(const float4*)(xbase + t * H);

#pragma unroll 1
    for (int hc = 0; hc < 128; hc += 4) {
        const int hn = (hc + 4) & 127;   // wraps on last iter (L1-hot, in-bounds)
#pragma unroll
        for (int t = 0; t < T; ++t)
            nxt[t] = *(const float4*)(xbase + t * H + hn);

#pragma unroll
        for (int e = 0; e < E; ++e) {
            // 2-way broadcast read (halves differ) -> conflict-free
            const float4 wv = *(const float4*)(w_lds + e * H + half * 128 + hc);
#pragma unroll
            for (int t = 0; t < T; ++t) {
                acc[e][t] += wv.x * cur[t].x + wv.y * cur[t].y
                           + wv.z * cur[t].z + wv.w * cur[t].w;
            }
        }
#pragma unroll
        for (int t = 0; t < T; ++t) cur[t] = nxt[t];
    }

    // ---- combine h-halves: both halves end with full logits ----
#pragma unroll
    for (int e = 0; e < E; ++e)
#pragma unroll
        for (int t = 0; t < T; ++t)
            acc[e][t] += __shfl_xor(acc[e][t], 32, 64);

    // ---- each lane finishes 2 tokens: half0 -> slots 0,1; half1 -> slots 2,3
    // L(e,s) = half ? acc[e][2+s] : acc[e][s]
    float m_s[2], inv_s[2];
    int   idx_s[2];
#pragma unroll
    for (int s = 0; s < 2; ++s) {
        float m = half ? acc[0][2 + s] : acc[0][s];
        int   id = 0;
#pragma unroll
        for (int e = 1; e < E; ++e) {
            const float v = half ? acc[e][2 + s] : acc[e][s];
            if (v > m) { m = v; id = e; }
        }
        float ss = 0.0f;
#pragma unroll
        for (int e = 0; e < E; ++e) {
            const float v = half ? acc[e][2 + s] : acc[e][s];
            ss += expf(v - m);
        }
        const float inv = 1.0f / ss;   // softmax score at argmax; SCALING = 1.0
        const int token = tok0 + half * 2 + s;
        out[token]        = (float)id;
        out[NTOK + token] = inv;
        m_s[s] = m; inv_s[s] = inv; idx_s[s] = id;
    }

    // ---- aux-loss accumulation: per-(batch,expert) count + score sum ----
    const int b = wavebase >> 13;   // /SEQ, wave-uniform

#pragma unroll 1
    for (int e = 0; e < E; ++e) {
        const float v0 = half ? acc[e][2] : acc[e][0];
        const float v1 = half ? acc[e][3] : acc[e][1];
        float sc = expf(v0 - m_s[0]) * inv_s[0] + expf(v1 - m_s[1]) * inv_s[1];
        float cn = (float)((idx_s[0] == e) + (idx_s[1] == e));
#pragma unroll
        for (int off = 32; off > 0; off >>= 1) {
            sc += __shfl_xor(sc, off, 64);
            cn += __shfl_xor(cn, off, 64);
        }
        if (lane == 0) {
            atomicAdd(&ws_sum[b * E + e], sc);
            if (cn != 0.0f) atomicAdd(&ws_cnt[b * E + e], cn);
        }
    }
}

// ---------------- aux loss reduction ----------------
__global__ __launch_bounds__(256) void aux_kernel(
    const float* __restrict__ ws_cnt, const float* __restrict__ ws_sum,
    float* __restrict__ out)
{
    const int tid = threadIdx.x;
    float p = 0.0f;
    for (int i = tid; i < BSZ * E; i += 256)
        p += ws_cnt[i] * ws_sum[i];

    __shared__ float red[4];
#pragma unroll
    for (int off = 32; off > 0; off >>= 1)
        p += __shfl_xor(p, off, 64);
    if ((tid & 63) == 0) red[tid >> 6] = p;
    __syncthreads();
    if (tid == 0) {
        float t = red[0] + red[1] + red[2] + red[3];
        // aux = sum_be cnt*ssum * alpha / (B * (SEQ/E) * SEQ)
        out[2 * NTOK] = t * (0.001f / (16.0f * 256.0f * 8192.0f));
    }
}

extern "C" void kernel_launch(void* const* d_in, const int* in_sizes, int n_in,
                              void* d_out, int out_size, void* d_ws, size_t ws_size,
                              hipStream_t stream) {
    const float* x = (const float*)d_in[0];
    const float* w = (const float*)d_in[1];
    float* out    = (float*)d_out;
    float* ws     = (float*)d_ws;
    float* ws_cnt = ws;
    float* ws_sum = ws + BSZ * E;

    zero_ws_kernel<<<4, 256, 0, stream>>>(ws);
    gate_kernel<<<NTOK / 256, 128, 0, stream>>>(x, w, out, ws_cnt, ws_sum);
    aux_kernel<<<1, 256, 0, stream>>>(ws_cnt, ws_sum, out);
}